// Round 1
// baseline (1709.762 us; speedup 1.0000x reference)
//
#include <hip/hip_runtime.h>
#include <hip/hip_bf16.h>

#define N_NODES 50000
#define N_EDGES 800000
#define FDIM 64
#define N_GRAPHS 500
#define OUTF 10

// ---------------- degree / dinv ----------------
__global__ void deg_kernel(const int* __restrict__ dst, float* __restrict__ deg) {
    int e = blockIdx.x * blockDim.x + threadIdx.x;
    if (e < N_EDGES) atomicAdd(&deg[dst[e]], 1.0f);
}

__global__ void dinv_kernel(float* __restrict__ deg) {
    int i = blockIdx.x * blockDim.x + threadIdx.x;
    if (i < N_NODES) deg[i] = rsqrtf(deg[i] + 1.0f);  // +1 self-loop; deg>=1 guaranteed
}

// ---------------- dense GEMM: C[n,64] = A[n,64] @ W[64,64] ----------------
__global__ __launch_bounds__(256) void gemm64(const float* __restrict__ A,
                                              const float* __restrict__ W,
                                              float* __restrict__ C, int n) {
    __shared__ float Ws[64 * 64];
    __shared__ float As[4 * 64];
    int tid = threadIdx.x;
    #pragma unroll
    for (int i = 0; i < 16; ++i) Ws[tid + i * 256] = W[tid + i * 256];
    int ty = tid >> 6, col = tid & 63;
    int row = blockIdx.x * 4 + ty;
    if (row < n) As[ty * 64 + col] = A[row * 64 + col];
    __syncthreads();
    if (row >= n) return;
    float acc = 0.f;
    #pragma unroll
    for (int k = 0; k < 64; ++k) acc += As[ty * 64 + k] * Ws[k * 64 + col];
    C[row * 64 + col] = acc;
}

// ---------------- edge scatter: agg[dst] += h[src] * dinv[src]*dinv[dst] ----------------
// 16 threads per edge, 4 feats each (float4 load). Edges >= N_EDGES are self-loops.
__global__ void scatter_edges(const int* __restrict__ src, const int* __restrict__ dst,
                              const float* __restrict__ dinv, const float* __restrict__ h,
                              float* __restrict__ agg) {
    int gid = blockIdx.x * blockDim.x + threadIdx.x;
    int e = gid >> 4;
    if (e >= N_EDGES + N_NODES) return;
    int fi = (gid & 15) * 4;
    int s, d;
    if (e < N_EDGES) { s = src[e]; d = dst[e]; }
    else             { s = d = e - N_EDGES; }
    float norm = dinv[s] * dinv[d];
    float4 hv = *(const float4*)(h + (size_t)s * FDIM + fi);
    float* o = agg + (size_t)d * FDIM + fi;
    atomicAdd(o + 0, hv.x * norm);
    atomicAdd(o + 1, hv.y * norm);
    atomicAdd(o + 2, hv.z * norm);
    atomicAdd(o + 3, hv.w * norm);
}

// ---------------- bias + relu, in place ----------------
__global__ void bias_relu(float* __restrict__ a, const float* __restrict__ b) {
    int gid = blockIdx.x * blockDim.x + threadIdx.x;
    if (gid >= N_NODES * FDIM) return;
    a[gid] = fmaxf(a[gid] + b[gid & 63], 0.f);
}

// ---------------- mean-pool accumulation ----------------
__global__ void pool_kernel(const float* __restrict__ h, const int* __restrict__ batch,
                            float* __restrict__ pooled, float* __restrict__ cnt) {
    int gid = blockIdx.x * blockDim.x + threadIdx.x;
    int node = gid >> 4;
    if (node >= N_NODES) return;
    int fi = (gid & 15) * 4;
    int g = batch[node];
    float4 v = *(const float4*)(h + (size_t)node * FDIM + fi);
    float* o = pooled + (size_t)g * FDIM + fi;
    atomicAdd(o + 0, v.x);
    atomicAdd(o + 1, v.y);
    atomicAdd(o + 2, v.z);
    atomicAdd(o + 3, v.w);
    if (fi == 0) atomicAdd(&cnt[g], 1.0f);
}

// ---------------- head: pooled/cnt @ Wc + bc, log_softmax ----------------
__global__ __launch_bounds__(64) void head_kernel(const float* __restrict__ pooled,
                                                  const float* __restrict__ cnt,
                                                  const float* __restrict__ Wc,
                                                  const float* __restrict__ bc,
                                                  float* __restrict__ out) {
    int g = blockIdx.x;
    int t = threadIdx.x;
    __shared__ float p[64];
    __shared__ float logits[OUTF];
    float c = fmaxf(cnt[g], 1.0f);
    p[t] = pooled[g * 64 + t] / c;
    __syncthreads();
    if (t < OUTF) {
        float acc = bc[t];
        #pragma unroll
        for (int k = 0; k < 64; ++k) acc += p[k] * Wc[k * OUTF + t];
        logits[t] = acc;
    }
    __syncthreads();
    if (t == 0) {
        float m = -1e30f;
        #pragma unroll
        for (int i = 0; i < OUTF; ++i) m = fmaxf(m, logits[i]);
        float s = 0.f;
        #pragma unroll
        for (int i = 0; i < OUTF; ++i) s += __expf(logits[i] - m);
        float lse = m + __logf(s);
        #pragma unroll
        for (int i = 0; i < OUTF; ++i) out[g * OUTF + i] = logits[i] - lse;
    }
}

extern "C" void kernel_launch(void* const* d_in, const int* in_sizes, int n_in,
                              void* d_out, int out_size, void* d_ws, size_t ws_size,
                              hipStream_t stream) {
    const float* x     = (const float*)d_in[0];
    const int*   ei    = (const int*)d_in[1];   // [2, N_EDGES]: row0=src, row1=dst
    const int*   batch = (const int*)d_in[2];
    const float* W1    = (const float*)d_in[3];
    const float* b1    = (const float*)d_in[4];
    const float* W2    = (const float*)d_in[5];
    const float* b2    = (const float*)d_in[6];
    const float* Wc    = (const float*)d_in[7];
    const float* bc    = (const float*)d_in[8];
    float* out = (float*)d_out;

    const int* src = ei;
    const int* dst = ei + N_EDGES;

    // workspace layout (floats)
    float* dinv   = (float*)d_ws;                  // 50000
    float* bufH   = dinv + N_NODES;                // 3.2M
    float* bufAgg = bufH + (size_t)N_NODES * FDIM; // 3.2M
    float* pooled = bufAgg + (size_t)N_NODES * FDIM; // 32000
    float* cnt    = pooled + (size_t)N_GRAPHS * FDIM; // 500

    // degrees -> dinv
    hipMemsetAsync(dinv, 0, N_NODES * sizeof(float), stream);
    deg_kernel<<<(N_EDGES + 255) / 256, 256, 0, stream>>>(dst, dinv);
    dinv_kernel<<<(N_NODES + 255) / 256, 256, 0, stream>>>(dinv);

    const int gemmGrid = (N_NODES + 3) / 4;
    const int scatterGrid = ((N_EDGES + N_NODES) * 16 + 255) / 256;
    const int brGrid = (N_NODES * FDIM + 255) / 256;

    // layer 1
    gemm64<<<gemmGrid, 256, 0, stream>>>(x, W1, bufH, N_NODES);
    hipMemsetAsync(bufAgg, 0, (size_t)N_NODES * FDIM * sizeof(float), stream);
    scatter_edges<<<scatterGrid, 256, 0, stream>>>(src, dst, dinv, bufH, bufAgg);
    bias_relu<<<brGrid, 256, 0, stream>>>(bufAgg, b1);

    // layer 2
    gemm64<<<gemmGrid, 256, 0, stream>>>(bufAgg, W2, bufH, N_NODES);
    hipMemsetAsync(bufAgg, 0, (size_t)N_NODES * FDIM * sizeof(float), stream);
    scatter_edges<<<scatterGrid, 256, 0, stream>>>(src, dst, dinv, bufH, bufAgg);
    bias_relu<<<brGrid, 256, 0, stream>>>(bufAgg, b2);

    // pool
    hipMemsetAsync(pooled, 0, (size_t)N_GRAPHS * FDIM * sizeof(float), stream);
    hipMemsetAsync(cnt, 0, N_GRAPHS * sizeof(float), stream);
    pool_kernel<<<(N_NODES * 16 + 255) / 256, 256, 0, stream>>>(bufAgg, batch, pooled, cnt);

    // head
    head_kernel<<<N_GRAPHS, 64, 0, stream>>>(pooled, cnt, Wc, bc, out);
}

// Round 2
// 348.157 us; speedup vs baseline: 4.9109x; 4.9109x over previous
//
#include <hip/hip_runtime.h>
#include <hip/hip_bf16.h>

#define N_NODES 50000
#define N_EDGES 800000
#define FDIM 64
#define N_GRAPHS 500
#define OUTF 10

// ---------------- CSR build ----------------
__global__ void count_deg(const int* __restrict__ dst, int* __restrict__ deg) {
    int e = blockIdx.x * blockDim.x + threadIdx.x;
    if (e < N_EDGES) atomicAdd(&deg[dst[e]], 1);
}

// rowptr[n] = disjoint range of size deg[n] (order irrelevant); dinv = rsqrt(deg+1)
__global__ void alloc_rows(const int* __restrict__ deg, int* __restrict__ rowptr,
                           float* __restrict__ dinv, int* __restrict__ cursor) {
    int i = blockIdx.x * blockDim.x + threadIdx.x;
    if (i >= N_NODES) return;
    int d = deg[i];
    rowptr[i] = atomicAdd(cursor, d);
    dinv[i] = rsqrtf((float)d + 1.0f);  // +1 for self-loop; always >= 1
}

__global__ void fill_csr(const int* __restrict__ src, const int* __restrict__ dst,
                         const int* __restrict__ rowptr, int* __restrict__ fill,
                         int* __restrict__ csr_src) {
    int e = blockIdx.x * blockDim.x + threadIdx.x;
    if (e >= N_EDGES) return;
    int d = dst[e];
    int pos = rowptr[d] + atomicAdd(&fill[d], 1);
    csr_src[pos] = src[e];
}

// batch is sorted: start[g] = first node with batch >= g; start[N_GRAPHS] = N_NODES
__global__ void seg_starts(const int* __restrict__ batch, int* __restrict__ start) {
    int i = blockIdx.x * blockDim.x + threadIdx.x;
    if (i > N_NODES) return;
    int b  = (i < N_NODES) ? batch[i] : N_GRAPHS;
    int bp = (i == 0) ? -1 : batch[i - 1];
    for (int g = bp + 1; g <= b; ++g) start[g] = i;
}

// ---------------- dense GEMM: C[n,64] = A[n,64] @ W[64,64] ----------------
__global__ __launch_bounds__(256) void gemm64(const float* __restrict__ A,
                                              const float* __restrict__ W,
                                              float* __restrict__ C, int n) {
    __shared__ float Ws[64 * 64];
    __shared__ float As[4 * 64];
    int tid = threadIdx.x;
    #pragma unroll
    for (int i = 0; i < 16; ++i) Ws[tid + i * 256] = W[tid + i * 256];
    int ty = tid >> 6, col = tid & 63;
    int row = blockIdx.x * 4 + ty;
    if (row < n) As[ty * 64 + col] = A[row * 64 + col];
    __syncthreads();
    if (row >= n) return;
    float acc = 0.f;
    #pragma unroll
    for (int k = 0; k < 64; ++k) acc += As[ty * 64 + k] * Ws[k * 64 + col];
    C[row * 64 + col] = acc;
}

// ---------------- per-node gather aggregation (no atomics) ----------------
// one wave per node, lane = feature. out[n] = relu(dinv[n]*acc + bias) where
// acc = dinv[n]*h[n] + sum_e dinv[src_e]*h[src_e]
__global__ __launch_bounds__(256) void gather_nodes(
    const int* __restrict__ rowptr, const int* __restrict__ deg,
    const int* __restrict__ csr_src, const float* __restrict__ dinv,
    const float* __restrict__ h, const float* __restrict__ bias,
    float* __restrict__ out) {
    int wave = (blockIdx.x * blockDim.x + threadIdx.x) >> 6;
    int lane = threadIdx.x & 63;
    if (wave >= N_NODES) return;
    int n = wave;
    float dn = dinv[n];
    int row = rowptr[n];
    int d = deg[n];
    float acc = dn * h[(size_t)n * FDIM + lane];  // self loop
    for (int base = 0; base < d; base += 64) {
        int cnt = min(64, d - base);
        int s = 0; float a = 0.f;
        if (lane < cnt) { s = csr_src[row + base + lane]; a = dinv[s]; }
        for (int j = 0; j < cnt; ++j) {
            int   sj = __shfl(s, j);
            float aj = __shfl(a, j);
            acc += aj * h[(size_t)sj * FDIM + lane];
        }
    }
    float v = dn * acc + bias[lane];
    out[(size_t)n * FDIM + lane] = fmaxf(v, 0.f);
}

// ---------------- fused mean-pool + head + log_softmax ----------------
__global__ __launch_bounds__(256) void pool_head(
    const float* __restrict__ h, const int* __restrict__ start,
    const float* __restrict__ Wc, const float* __restrict__ bc,
    float* __restrict__ out) {
    int g = blockIdx.x;
    int lane = threadIdx.x & 63, w = threadIdx.x >> 6;
    int s0 = start[g], s1 = start[g + 1];
    float sum = 0.f;
    for (int i = s0 + w; i < s1; i += 4) sum += h[(size_t)i * FDIM + lane];
    __shared__ float ps[4][64];
    __shared__ float logits[OUTF];
    ps[w][lane] = sum;
    __syncthreads();
    if (threadIdx.x < 64) {
        float tot = ps[0][lane] + ps[1][lane] + ps[2][lane] + ps[3][lane];
        float c = (float)((s1 - s0) > 1 ? (s1 - s0) : 1);
        ps[0][lane] = tot / c;
    }
    __syncthreads();
    if (threadIdx.x < OUTF) {
        float acc = bc[threadIdx.x];
        #pragma unroll
        for (int k = 0; k < 64; ++k) acc += ps[0][k] * Wc[k * OUTF + threadIdx.x];
        logits[threadIdx.x] = acc;
    }
    __syncthreads();
    if (threadIdx.x == 0) {
        float m = -1e30f;
        #pragma unroll
        for (int i = 0; i < OUTF; ++i) m = fmaxf(m, logits[i]);
        float s = 0.f;
        #pragma unroll
        for (int i = 0; i < OUTF; ++i) s += __expf(logits[i] - m);
        float lse = m + __logf(s);
        #pragma unroll
        for (int i = 0; i < OUTF; ++i) out[g * OUTF + i] = logits[i] - lse;
    }
}

extern "C" void kernel_launch(void* const* d_in, const int* in_sizes, int n_in,
                              void* d_out, int out_size, void* d_ws, size_t ws_size,
                              hipStream_t stream) {
    const float* x     = (const float*)d_in[0];
    const int*   ei    = (const int*)d_in[1];   // [2, N_EDGES]: row0=src, row1=dst
    const int*   batch = (const int*)d_in[2];
    const float* W1    = (const float*)d_in[3];
    const float* b1    = (const float*)d_in[4];
    const float* W2    = (const float*)d_in[5];
    const float* b2    = (const float*)d_in[6];
    const float* Wc    = (const float*)d_in[7];
    const float* bc    = (const float*)d_in[8];
    float* out = (float*)d_out;

    const int* src = ei;
    const int* dst = ei + N_EDGES;

    // workspace layout (all 4-byte elems)
    int*   deg     = (int*)d_ws;                 // 50000   } zeroed
    int*   fill    = deg + N_NODES;              // 50000   } together
    int*   cursor  = fill + N_NODES;             // 1       }
    int*   rowptr  = cursor + 1;                 // 50000
    float* dinv    = (float*)(rowptr + N_NODES); // 50000
    int*   start   = (int*)(dinv + N_NODES);     // 501
    int*   csr_src = start + (N_GRAPHS + 1);     // 800000
    float* bufH    = (float*)(csr_src + N_EDGES);        // 3.2M
    float* bufAgg  = bufH + (size_t)N_NODES * FDIM;      // 3.2M

    hipMemsetAsync(deg, 0, (2 * N_NODES + 1) * sizeof(int), stream);

    count_deg <<<(N_EDGES + 255) / 256, 256, 0, stream>>>(dst, deg);
    alloc_rows<<<(N_NODES + 255) / 256, 256, 0, stream>>>(deg, rowptr, dinv, cursor);
    fill_csr  <<<(N_EDGES + 255) / 256, 256, 0, stream>>>(src, dst, rowptr, fill, csr_src);
    seg_starts<<<(N_NODES + 256) / 256, 256, 0, stream>>>(batch, start);

    const int gemmGrid = (N_NODES + 3) / 4;
    const int gathGrid = (N_NODES + 3) / 4;  // 4 waves/block, 1 wave/node

    // layer 1
    gemm64<<<gemmGrid, 256, 0, stream>>>(x, W1, bufH, N_NODES);
    gather_nodes<<<gathGrid, 256, 0, stream>>>(rowptr, deg, csr_src, dinv, bufH, b1, bufAgg);

    // layer 2
    gemm64<<<gemmGrid, 256, 0, stream>>>(bufAgg, W2, bufH, N_NODES);
    gather_nodes<<<gathGrid, 256, 0, stream>>>(rowptr, deg, csr_src, dinv, bufH, b2, bufAgg);

    // fused pool + head
    pool_head<<<N_GRAPHS, 256, 0, stream>>>(bufAgg, start, Wc, bc, out);
}

// Round 3
// 262.711 us; speedup vs baseline: 6.5081x; 1.3252x over previous
//
#include <hip/hip_runtime.h>
#include <hip/hip_bf16.h>

#define N_NODES 50000
#define N_EDGES 800000
#define FDIM 64
#define N_GRAPHS 500
#define OUTF 10

__device__ __forceinline__ float rl(float v, int l) {
    return __int_as_float(__builtin_amdgcn_readlane(__float_as_int(v), l));
}

struct EdgeRec { int s; float a; };

// ---------------- CSR build ----------------
__global__ void count_deg(const int* __restrict__ dst, int* __restrict__ deg) {
    int e = blockIdx.x * blockDim.x + threadIdx.x;
    if (e < N_EDGES) atomicAdd(&deg[dst[e]], 1);
}

__global__ void alloc_rows(const int* __restrict__ deg, int* __restrict__ rowptr,
                           float* __restrict__ dinv, int* __restrict__ cursor) {
    int i = blockIdx.x * blockDim.x + threadIdx.x;
    if (i >= N_NODES) return;
    int d = deg[i];
    rowptr[i] = atomicAdd(cursor, d);
    dinv[i] = rsqrtf((float)d + 1.0f);  // +1 self-loop
}

__global__ void fill_csr(const int* __restrict__ src, const int* __restrict__ dst,
                         const int* __restrict__ rowptr, int* __restrict__ fill,
                         const float* __restrict__ dinv, EdgeRec* __restrict__ csr) {
    int e = blockIdx.x * blockDim.x + threadIdx.x;
    if (e >= N_EDGES) return;
    int s = src[e], d = dst[e];
    int pos = rowptr[d] + atomicAdd(&fill[d], 1);
    EdgeRec r; r.s = s; r.a = dinv[s];
    csr[pos] = r;
}

// batch sorted: start[g] = first node with batch >= g; start[N_GRAPHS] = N_NODES
__global__ void seg_starts(const int* __restrict__ batch, int* __restrict__ start) {
    int i = blockIdx.x * blockDim.x + threadIdx.x;
    if (i > N_NODES) return;
    int b  = (i < N_NODES) ? batch[i] : N_GRAPHS;
    int bp = (i == 0) ? -1 : batch[i - 1];
    for (int g = bp + 1; g <= b; ++g) start[g] = i;
}

// ---------------- fused GCN layer: out = relu( (D^-1/2 (A+I) D^-1/2 h) @ W + b ) ----------------
// one wave = 4 nodes (16-lane group per node, lane L holds feats [4L..4L+3] as float4)
__global__ __launch_bounds__(256) void gcn_fused(
    const int* __restrict__ rowptr, const int* __restrict__ deg,
    const EdgeRec* __restrict__ csr, const float* __restrict__ dinv,
    const float* __restrict__ h, const float* __restrict__ W,
    const float* __restrict__ bias, float* __restrict__ out) {
    __shared__ float Ws[FDIM * FDIM];
    int tid = threadIdx.x;
    int lane = tid & 63;
    int L = lane & 15, q = lane >> 4;
    int nodeBase = (blockIdx.x * 4 + (tid >> 6)) * 4;   // 16 nodes/block, grid=3125 exact
    int myN = nodeBase + q;

    float dn = dinv[myN];
    int row = rowptr[myN];
    int d   = deg[myN];
    int maxd = d;
    maxd = max(maxd, __shfl_xor(maxd, 16));
    maxd = max(maxd, __shfl_xor(maxd, 32));

    // self-loop term
    const float4 xs = *(const float4*)(h + (size_t)myN * FDIM + 4 * L);
    float accx = dn * xs.x, accy = dn * xs.y, accz = dn * xs.z, accw = dn * xs.w;

    // stage W while the above loads are in flight
    #pragma unroll
    for (int i = 0; i < 16; ++i) Ws[tid + i * 256] = W[tid + i * 256];
    __syncthreads();

    // edge aggregation: branch-free, 8 rows in flight per wave
    for (int base = 0; base < maxd; base += 8) {
        #pragma unroll
        for (int j = 0; j < 8; ++j) {
            int e = base + j;
            int idx = row + e;
            if (idx > N_EDGES - 1) idx = N_EDGES - 1;   // clamp: stay in-bounds
            EdgeRec r = csr[idx];
            float aj = (e < d) ? r.a : 0.f;             // mask invalid (branch-free)
            const float4 hv = *(const float4*)(h + (size_t)r.s * FDIM + 4 * L);
            accx = fmaf(aj, hv.x, accx);
            accy = fmaf(aj, hv.y, accy);
            accz = fmaf(aj, hv.z, accz);
            accw = fmaf(aj, hv.w, accw);
        }
    }
    accx *= dn; accy *= dn; accz *= dn; accw *= dn;

    // matvec: out[nodeBase+q][c=lane] = relu(sum_k agg_q[k]*W[k][c] + b[c])
    float b0 = bias[lane];
    float o0 = b0, o1 = b0, o2 = b0, o3 = b0;
    #pragma unroll
    for (int k = 0; k < 64; ++k) {
        float wv = Ws[k * 64 + lane];
        int sl = k >> 2;
        float comp = (k & 3) == 0 ? accx : (k & 3) == 1 ? accy : (k & 3) == 2 ? accz : accw;
        o0 = fmaf(rl(comp, sl),      wv, o0);
        o1 = fmaf(rl(comp, sl + 16), wv, o1);
        o2 = fmaf(rl(comp, sl + 32), wv, o2);
        o3 = fmaf(rl(comp, sl + 48), wv, o3);
    }
    out[(size_t)(nodeBase + 0) * FDIM + lane] = fmaxf(o0, 0.f);
    out[(size_t)(nodeBase + 1) * FDIM + lane] = fmaxf(o1, 0.f);
    out[(size_t)(nodeBase + 2) * FDIM + lane] = fmaxf(o2, 0.f);
    out[(size_t)(nodeBase + 3) * FDIM + lane] = fmaxf(o3, 0.f);
}

// ---------------- fused mean-pool + head + log_softmax ----------------
__global__ __launch_bounds__(256) void pool_head(
    const float* __restrict__ h, const int* __restrict__ start,
    const float* __restrict__ Wc, const float* __restrict__ bc,
    float* __restrict__ out) {
    int g = blockIdx.x;
    int tid = threadIdx.x;
    int lane = tid & 63, w = tid >> 6;
    int L = lane & 15, q = lane >> 4;
    int s0 = start[g], s1 = start[g + 1];
    int sub = w * 4 + q;  // 0..15

    float4 acc = make_float4(0.f, 0.f, 0.f, 0.f);
    for (int i = s0 + sub; i < s1; i += 16) {
        const float4 v = *(const float4*)(h + (size_t)i * FDIM + 4 * L);
        acc.x += v.x; acc.y += v.y; acc.z += v.z; acc.w += v.w;
    }
    // reduce over the 4 groups in this wave
    #pragma unroll
    for (int m = 16; m <= 32; m <<= 1) {
        acc.x += __shfl_xor(acc.x, m);
        acc.y += __shfl_xor(acc.y, m);
        acc.z += __shfl_xor(acc.z, m);
        acc.w += __shfl_xor(acc.w, m);
    }
    __shared__ float ps[4 * 64];
    __shared__ float pm[64];
    __shared__ float logits[OUTF];
    if (q == 0) *(float4*)(ps + w * 64 + 4 * L) = acc;
    __syncthreads();
    if (tid < 64) {
        float tot = ps[tid] + ps[64 + tid] + ps[128 + tid] + ps[192 + tid];
        float c = (float)((s1 - s0) > 1 ? (s1 - s0) : 1);
        pm[tid] = tot / c;
    }
    __syncthreads();
    if (tid < OUTF) {
        float a = bc[tid];
        #pragma unroll
        for (int k = 0; k < 64; ++k) a = fmaf(pm[k], Wc[k * OUTF + tid], a);
        logits[tid] = a;
    }
    __syncthreads();
    if (tid == 0) {
        float m = -1e30f;
        #pragma unroll
        for (int i = 0; i < OUTF; ++i) m = fmaxf(m, logits[i]);
        float s = 0.f;
        #pragma unroll
        for (int i = 0; i < OUTF; ++i) s += __expf(logits[i] - m);
        float lse = m + __logf(s);
        #pragma unroll
        for (int i = 0; i < OUTF; ++i) out[g * OUTF + i] = logits[i] - lse;
    }
}

extern "C" void kernel_launch(void* const* d_in, const int* in_sizes, int n_in,
                              void* d_out, int out_size, void* d_ws, size_t ws_size,
                              hipStream_t stream) {
    const float* x     = (const float*)d_in[0];
    const int*   ei    = (const int*)d_in[1];
    const int*   batch = (const int*)d_in[2];
    const float* W1    = (const float*)d_in[3];
    const float* b1    = (const float*)d_in[4];
    const float* W2    = (const float*)d_in[5];
    const float* b2    = (const float*)d_in[6];
    const float* Wc    = (const float*)d_in[7];
    const float* bc    = (const float*)d_in[8];
    float* out = (float*)d_out;

    const int* src = ei;
    const int* dst = ei + N_EDGES;

    // workspace layout
    int*     deg     = (int*)d_ws;                     // 50000 } zeroed
    int*     fill    = deg + N_NODES;                  // 50000 } together
    int*     cursor  = fill + N_NODES;                 // 1     }
    int*     rowptr  = cursor + 1;                     // 50000
    float*   dinv    = (float*)(rowptr + N_NODES);     // 50000
    int*     start   = (int*)(dinv + N_NODES);         // 501
    EdgeRec* csr     = (EdgeRec*)(start + N_GRAPHS + 3); // 800000 * 8B (8-byte aligned)
    float*   bufH    = (float*)(csr + N_EDGES);        // 3.2M
    float*   bufAgg  = bufH + (size_t)N_NODES * FDIM;  // 3.2M

    hipMemsetAsync(deg, 0, (2 * N_NODES + 1) * sizeof(int), stream);

    count_deg <<<(N_EDGES + 255) / 256, 256, 0, stream>>>(dst, deg);
    alloc_rows<<<(N_NODES + 255) / 256, 256, 0, stream>>>(deg, rowptr, dinv, cursor);
    fill_csr  <<<(N_EDGES + 255) / 256, 256, 0, stream>>>(src, dst, rowptr, fill, dinv, csr);
    seg_starts<<<(N_NODES + 256) / 256, 256, 0, stream>>>(batch, start);

    const int gcnGrid = N_NODES / 16;  // 3125, exact

    gcn_fused<<<gcnGrid, 256, 0, stream>>>(rowptr, deg, csr, dinv, x,      W1, b1, bufH);
    gcn_fused<<<gcnGrid, 256, 0, stream>>>(rowptr, deg, csr, dinv, bufH,   W2, b2, bufAgg);

    pool_head<<<N_GRAPHS, 256, 0, stream>>>(bufAgg, start, Wc, bc, out);
}

// Round 4
// 257.096 us; speedup vs baseline: 6.6503x; 1.0218x over previous
//
#include <hip/hip_runtime.h>
#include <hip/hip_bf16.h>

#define N_NODES 50000
#define N_EDGES 800000
#define FDIM 64
#define N_GRAPHS 500
#define OUTF 10
#define CSR_CAP (N_EDGES + 8 * N_NODES)   // padded-to-8 worst case

__device__ __forceinline__ float rl(float v, int l) {
    return __int_as_float(__builtin_amdgcn_readlane(__float_as_int(v), l));
}

// ---------------- degree count + zero the two sentinel rows ----------------
__global__ void count_deg(const int* __restrict__ dst, int* __restrict__ deg,
                          float* __restrict__ sent0, float* __restrict__ sent1) {
    if (blockIdx.x == 0 && threadIdx.x < 2 * FDIM) {
        if (threadIdx.x < FDIM) sent0[threadIdx.x] = 0.f;
        else                    sent1[threadIdx.x - FDIM] = 0.f;
    }
    int e = blockIdx.x * blockDim.x + threadIdx.x;
    if (e < N_EDGES) atomicAdd(&deg[dst[e]], 1);
}

// ---------------- row allocation: block-scan + ONE cursor atomic per block ----------------
// rowinfo[n] = {base, padded_len}; pad region pre-filled with sentinel src = N_NODES
__global__ __launch_bounds__(256) void alloc_rows(
    const int* __restrict__ deg, int2* __restrict__ rowinfo,
    float* __restrict__ dinv, int* __restrict__ cursor, int* __restrict__ csr_src) {
    int i = blockIdx.x * blockDim.x + threadIdx.x;
    int d = (i < N_NODES) ? deg[i] : 0;
    int dpad = (d + 7) & ~7;
    if (dpad == 0) dpad = 8;               // keep clamp target valid even for deg==0
    if (i >= N_NODES) dpad = 0;

    int lane = threadIdx.x & 63, w = threadIdx.x >> 6;
    int v = dpad;                           // inclusive wave scan
    #pragma unroll
    for (int off = 1; off < 64; off <<= 1) {
        int t = __shfl_up(v, off);
        if (lane >= off) v += t;
    }
    __shared__ int wsum[4];
    __shared__ int base;
    if (lane == 63) wsum[w] = v;
    __syncthreads();
    if (threadIdx.x == 0) {
        int run = 0;
        #pragma unroll
        for (int k = 0; k < 4; ++k) { int t = wsum[k]; wsum[k] = run; run += t; }
        base = atomicAdd(cursor, run);      // 196 atomics total, order irrelevant
    }
    __syncthreads();
    if (i < N_NODES) {
        int my = base + wsum[w] + (v - dpad);
        rowinfo[i] = make_int2(my, dpad);
        dinv[i] = rsqrtf((float)d + 1.0f);
        for (int k = d; k < dpad; ++k) csr_src[my + k] = N_NODES;  // sentinel pad
    }
}

__global__ void fill_csr(const int* __restrict__ src, const int* __restrict__ dst,
                         const int2* __restrict__ rowinfo, int* __restrict__ fill,
                         int* __restrict__ csr_src) {
    int e = blockIdx.x * blockDim.x + threadIdx.x;
    if (e >= N_EDGES) return;
    int s = src[e], d = dst[e];
    int pos = rowinfo[d].x + atomicAdd(&fill[d], 1);
    csr_src[pos] = s;
}

// batch sorted: start[g] = first node with batch >= g; start[N_GRAPHS] = N_NODES
__global__ void seg_starts(const int* __restrict__ batch, int* __restrict__ start) {
    int i = blockIdx.x * blockDim.x + threadIdx.x;
    if (i > N_NODES) return;
    int b  = (i < N_NODES) ? batch[i] : N_GRAPHS;
    int bp = (i == 0) ? -1 : batch[i - 1];
    for (int g = bp + 1; g <= b; ++g) start[g] = i;
}

// hs_x[n] = dinv[n] * x[n]
__global__ void prescale(const float* __restrict__ x, const float* __restrict__ dinv,
                         float* __restrict__ hs) {
    int gid = blockIdx.x * blockDim.x + threadIdx.x;
    if (gid >= N_NODES * 16) return;
    float dn = dinv[gid >> 4];
    float4 v = ((const float4*)x)[gid];
    v.x *= dn; v.y *= dn; v.z *= dn; v.w *= dn;
    ((float4*)hs)[gid] = v;
}

// ---------------- fused GCN layer ----------------
// input hs is pre-scaled by dinv. out = relu(dn * (hs[n] + sum hs[src]) @ W + b),
// optionally re-scaled by dinv for the next layer's gather (SCALE_OUT).
template <bool SCALE_OUT>
__global__ __launch_bounds__(256) void gcn_fused(
    const int2* __restrict__ rowinfo, const int* __restrict__ csr_src,
    const float* __restrict__ dinv, const float* __restrict__ hs,
    const float* __restrict__ W, const float* __restrict__ bias,
    float* __restrict__ out) {
    __shared__ float Ws[FDIM * FDIM];
    int tid = threadIdx.x;
    int lane = tid & 63;
    int L = lane & 15, q = lane >> 4;
    int nodeBase = (blockIdx.x * 4 + (tid >> 6)) * 4;   // grid = 3125, exact
    int myN = nodeBase + q;

    float dn = dinv[myN];
    int2 ri = rowinfo[myN];
    int row = ri.x, dpad = ri.y;
    int rowLast = row + dpad - 1;
    int maxd = dpad;
    maxd = max(maxd, __shfl_xor(maxd, 16));
    maxd = max(maxd, __shfl_xor(maxd, 32));

    float4 acc = *(const float4*)(hs + (size_t)myN * FDIM + 4 * L);  // self term

    #pragma unroll
    for (int i = 0; i < 16; ++i) Ws[tid + i * 256] = W[tid + i * 256];
    __syncthreads();

    // tail iterations clamp to this node's own sentinel slot (cached zero row)
    for (int base = 0; base < maxd; base += 8) {
        #pragma unroll
        for (int j = 0; j < 8; ++j) {
            int idx = min(row + base + j, rowLast);
            int s = csr_src[idx];
            const float4 hv = *(const float4*)(hs + (size_t)s * FDIM + 4 * L);
            acc.x += hv.x; acc.y += hv.y; acc.z += hv.z; acc.w += hv.w;
        }
    }
    acc.x *= dn; acc.y *= dn; acc.z *= dn; acc.w *= dn;

    float b0 = bias[lane];
    float o0 = b0, o1 = b0, o2 = b0, o3 = b0;
    #pragma unroll
    for (int k = 0; k < 64; ++k) {
        float wv = Ws[k * 64 + lane];
        int sl = k >> 2;
        float comp = (k & 3) == 0 ? acc.x : (k & 3) == 1 ? acc.y : (k & 3) == 2 ? acc.z : acc.w;
        o0 = fmaf(rl(comp, sl),      wv, o0);
        o1 = fmaf(rl(comp, sl + 16), wv, o1);
        o2 = fmaf(rl(comp, sl + 32), wv, o2);
        o3 = fmaf(rl(comp, sl + 48), wv, o3);
    }
    o0 = fmaxf(o0, 0.f); o1 = fmaxf(o1, 0.f); o2 = fmaxf(o2, 0.f); o3 = fmaxf(o3, 0.f);
    if (SCALE_OUT) {   // pre-scale rows for the next layer's gather
        o0 *= rl(dn, 0); o1 *= rl(dn, 16); o2 *= rl(dn, 32); o3 *= rl(dn, 48);
    }
    out[(size_t)(nodeBase + 0) * FDIM + lane] = o0;
    out[(size_t)(nodeBase + 1) * FDIM + lane] = o1;
    out[(size_t)(nodeBase + 2) * FDIM + lane] = o2;
    out[(size_t)(nodeBase + 3) * FDIM + lane] = o3;
}

// ---------------- fused mean-pool + head + log_softmax ----------------
__global__ __launch_bounds__(256) void pool_head(
    const float* __restrict__ h, const int* __restrict__ start,
    const float* __restrict__ Wc, const float* __restrict__ bc,
    float* __restrict__ out) {
    int g = blockIdx.x;
    int tid = threadIdx.x;
    int lane = tid & 63, w = tid >> 6;
    int L = lane & 15, q = lane >> 4;
    int s0 = start[g], s1 = start[g + 1];
    int sub = w * 4 + q;

    float4 acc = make_float4(0.f, 0.f, 0.f, 0.f);
    for (int i = s0 + sub; i < s1; i += 16) {
        const float4 v = *(const float4*)(h + (size_t)i * FDIM + 4 * L);
        acc.x += v.x; acc.y += v.y; acc.z += v.z; acc.w += v.w;
    }
    #pragma unroll
    for (int m = 16; m <= 32; m <<= 1) {
        acc.x += __shfl_xor(acc.x, m);
        acc.y += __shfl_xor(acc.y, m);
        acc.z += __shfl_xor(acc.z, m);
        acc.w += __shfl_xor(acc.w, m);
    }
    __shared__ float ps[4 * 64];
    __shared__ float pm[64];
    __shared__ float logits[OUTF];
    if (q == 0) *(float4*)(ps + w * 64 + 4 * L) = acc;
    __syncthreads();
    if (tid < 64) {
        float tot = ps[tid] + ps[64 + tid] + ps[128 + tid] + ps[192 + tid];
        float c = (float)((s1 - s0) > 1 ? (s1 - s0) : 1);
        pm[tid] = tot / c;
    }
    __syncthreads();
    if (tid < OUTF) {
        float a = bc[tid];
        #pragma unroll
        for (int k = 0; k < 64; ++k) a = fmaf(pm[k], Wc[k * OUTF + tid], a);
        logits[tid] = a;
    }
    __syncthreads();
    if (tid == 0) {
        float m = -1e30f;
        #pragma unroll
        for (int i = 0; i < OUTF; ++i) m = fmaxf(m, logits[i]);
        float s = 0.f;
        #pragma unroll
        for (int i = 0; i < OUTF; ++i) s += __expf(logits[i] - m);
        float lse = m + __logf(s);
        #pragma unroll
        for (int i = 0; i < OUTF; ++i) out[g * OUTF + i] = logits[i] - lse;
    }
}

extern "C" void kernel_launch(void* const* d_in, const int* in_sizes, int n_in,
                              void* d_out, int out_size, void* d_ws, size_t ws_size,
                              hipStream_t stream) {
    const float* x     = (const float*)d_in[0];
    const int*   ei    = (const int*)d_in[1];
    const int*   batch = (const int*)d_in[2];
    const float* W1    = (const float*)d_in[3];
    const float* b1    = (const float*)d_in[4];
    const float* W2    = (const float*)d_in[5];
    const float* b2    = (const float*)d_in[6];
    const float* Wc    = (const float*)d_in[7];
    const float* bc    = (const float*)d_in[8];
    float* out = (float*)d_out;

    const int* src = ei;
    const int* dst = ei + N_EDGES;

    // workspace layout (4-byte units; rowinfo 8-byte aligned)
    int*   deg     = (int*)d_ws;                        // 50000 } one
    int*   fill    = deg + N_NODES;                     // 50000 } memset
    int*   cursor  = fill + N_NODES;                    // 1     } (100001 ints)
    int*   pad0    = cursor + 1;                        // 1 (align)
    int2*  rowinfo = (int2*)(pad0 + 1);                 // 50000 int2
    float* dinv    = (float*)(rowinfo + N_NODES);       // 50000
    int*   start   = (int*)(dinv + N_NODES);            // 504
    int*   csr_src = start + N_GRAPHS + 4;              // CSR_CAP = 1.2M
    float* hsx     = (float*)(csr_src + CSR_CAP);       // (N_NODES+1)*64  (row N_NODES = sentinel zeros)
    float* hs1     = hsx + (size_t)(N_NODES + 1) * FDIM; // (N_NODES+1)*64
    float* out2    = hsx;                                // alias: hsx dead after layer 1

    hipMemsetAsync(deg, 0, (2 * N_NODES + 1) * sizeof(int), stream);

    count_deg <<<(N_EDGES + 255) / 256, 256, 0, stream>>>(
        dst, deg, hsx + (size_t)N_NODES * FDIM, hs1 + (size_t)N_NODES * FDIM);
    alloc_rows<<<(N_NODES + 255) / 256, 256, 0, stream>>>(deg, rowinfo, dinv, cursor, csr_src);
    prescale  <<<(N_NODES * 16 + 255) / 256, 256, 0, stream>>>(x, dinv, hsx);
    fill_csr  <<<(N_EDGES + 255) / 256, 256, 0, stream>>>(src, dst, rowinfo, fill, csr_src);
    seg_starts<<<(N_NODES + 256) / 256, 256, 0, stream>>>(batch, start);

    const int gcnGrid = N_NODES / 16;  // 3125, exact

    gcn_fused<true ><<<gcnGrid, 256, 0, stream>>>(rowinfo, csr_src, dinv, hsx, W1, b1, hs1);
    gcn_fused<false><<<gcnGrid, 256, 0, stream>>>(rowinfo, csr_src, dinv, hs1, W2, b2, out2);

    pool_head<<<N_GRAPHS, 256, 0, stream>>>(out2, start, Wc, bc, out);
}